// Round 14
// baseline (43.311 us; speedup 1.0000x reference)
//
#include <hip/hip_runtime.h>
#include <math.h>

// DETR HungarianMatcher cost matrix on MI355X — round 14.
// EXACT R7 kernel (best: 22.4us — f32 math, software-pipelined row loop,
// NT stores), single variable changed: __launch_bounds__(256,6) -> (256,8).
// 2000 blocks <= 256CU x 8 -> ALL blocks co-resident: prologues overlap
// once at t=0 instead of re-executing serially ~8x per CU.

#define NROWS 16000
#define NC 92
#define M_TGT 1024
#define TPB 256
#define ROWS 8
#define KPT 4   // consecutive targets per thread (KPT*TPB == M_TGT)

typedef float f32x4 __attribute__((ext_vector_type(4)));

__global__ __launch_bounds__(TPB, 8) void hungarian_cost_kernel(
    const float* __restrict__ logits,   // [NROWS, NC]
    const float* __restrict__ pboxes,   // [NROWS, 4] cxcywh
    const float* __restrict__ tboxes,   // [M_TGT, 4] cxcywh
    const int*   __restrict__ tlabels,  // [M_TGT]
    float* __restrict__ out)            // [NROWS, M_TGT]
{
    const int n0 = blockIdx.x * ROWS;
    const int t = threadIdx.x;
    const int lane = t & 63;
    const int wid  = t >> 6;

    __shared__ float negp[ROWS][NC];   // 2 - softmax prob

    // ---- softmax: wave `wid` handles rows 2*wid, 2*wid+1 ----
    #pragma unroll
    for (int j = 0; j < 2; ++j) {
        const int r = wid * 2 + j;
        const float* lg = logits + (size_t)(n0 + r) * NC;
        const float x0 = lg[lane];                 // lanes 0..63
        const bool  hi = (lane < NC - 64);         // lanes 0..27 cover 64..91
        const float x1 = hi ? lg[64 + lane] : -INFINITY;
        float mx = fmaxf(x0, x1);
        #pragma unroll
        for (int off = 32; off >= 1; off >>= 1)
            mx = fmaxf(mx, __shfl_xor(mx, off));
        const float e0 = __expf(x0 - mx);
        const float e1 = hi ? __expf(x1 - mx) : 0.0f;
        float s = e0 + e1;
        #pragma unroll
        for (int off = 32; off >= 1; off >>= 1)
            s += __shfl_xor(s, off);
        const float rs = __builtin_amdgcn_rcpf(s);
        negp[r][lane] = fmaf(-e0, rs, 2.0f);
        if (hi) negp[r][64 + lane] = fmaf(-e1, rs, 2.0f);
    }

    // ---- per-thread target context (registers), m = 4t + k ----
    float tcx[KPT], tcy[KPT], twd[KPT], tht[KPT];
    float bx0[KPT], by0[KPT], bx1[KPT], by1[KPT], areab[KPT];
    const int4 lb4 = reinterpret_cast<const int4*>(tlabels)[t];
    int lbl[KPT] = {lb4.x, lb4.y, lb4.z, lb4.w};
    #pragma unroll
    for (int k = 0; k < KPT; ++k) {
        const float4 tb = reinterpret_cast<const float4*>(tboxes)[4 * t + k];
        tcx[k] = tb.x; tcy[k] = tb.y; twd[k] = tb.z; tht[k] = tb.w;
        bx0[k] = fmaf(-0.5f, tb.z, tb.x);  by0[k] = fmaf(-0.5f, tb.w, tb.y);
        bx1[k] = fmaf( 0.5f, tb.z, tb.x);  by1[k] = fmaf( 0.5f, tb.w, tb.y);
        areab[k] = tb.z * tb.w;
        lbl[k] = (lbl[k] < 0) ? 0 : (lbl[k] > NC - 1 ? NC - 1 : lbl[k]);
    }
    __syncthreads();

    // ---- software-pipelined main loop over 8 rows ----
    float cls[KPT];
    #pragma unroll
    for (int k = 0; k < KPT; ++k) cls[k] = negp[0][lbl[k]];
    float4 pb = reinterpret_cast<const float4*>(pboxes)[n0];   // uniform

    #pragma unroll
    for (int r = 0; r < ROWS; ++r) {
        // prefetch next row's gathers + pred box (independent of this row)
        float clsN[KPT];
        float4 pbN;
        if (r + 1 < ROWS) {
            #pragma unroll
            for (int k = 0; k < KPT; ++k) clsN[k] = negp[r + 1][lbl[k]];
            pbN = reinterpret_cast<const float4*>(pboxes)[n0 + r + 1];
        }

        const float ax0 = fmaf(-0.5f, pb.z, pb.x);
        const float ay0 = fmaf(-0.5f, pb.w, pb.y);
        const float ax1 = fmaf( 0.5f, pb.z, pb.x);
        const float ay1 = fmaf( 0.5f, pb.w, pb.y);
        const float area_a = pb.z * pb.w;

        float tmp[KPT];
        #pragma unroll
        for (int k = 0; k < KPT; ++k) {
            const float cb = fabsf(pb.x - tcx[k]) + fabsf(pb.y - tcy[k])
                           + fabsf(pb.z - twd[k]) + fabsf(pb.w - tht[k]);
            const float iwu = fminf(ax1, bx1[k]) - fmaxf(ax0, bx0[k]);
            const float ihu = fminf(ay1, by1[k]) - fmaxf(ay0, by0[k]);
            const float inter = fmaxf(iwu, 0.0f) * fmaxf(ihu, 0.0f);
            const float uni = area_a + areab[k] - inter;
            const float ew = pb.z + twd[k] - iwu;   // max(a1,b1)-min(a0,b0)
            const float eh = pb.w + tht[k] - ihu;
            const float ae = ew * eh;
            const float h = fmaf(inter, __builtin_amdgcn_rcpf(uni),
                                 uni * __builtin_amdgcn_rcpf(ae));
            tmp[k] = fmaf(5.0f, cb, cls[k]) - 2.0f * h;
        }
        f32x4 res = {tmp[0], tmp[1], tmp[2], tmp[3]};
        __builtin_nontemporal_store(res,
            reinterpret_cast<f32x4*>(out + ((size_t)(n0 + r) << 10)) + t);

        #pragma unroll
        for (int k = 0; k < KPT; ++k) cls[k] = clsN[k];
        pb = pbN;
    }
}

extern "C" void kernel_launch(void* const* d_in, const int* in_sizes, int n_in,
                              void* d_out, int out_size, void* d_ws, size_t ws_size,
                              hipStream_t stream) {
    const float* logits  = (const float*)d_in[0];  // [16,1000,92]
    const float* pboxes  = (const float*)d_in[1];  // [16,1000,4]
    const float* tboxes  = (const float*)d_in[2];  // [1024,4]
    const int*   tlabels = (const int*)d_in[3];    // [1024]
    float* out = (float*)d_out;                    // [16,1000,1024]

    hungarian_cost_kernel<<<NROWS / ROWS, TPB, 0, stream>>>(
        logits, pboxes, tboxes, tlabels, out);
}

// Round 15
// 24.466 us; speedup vs baseline: 1.7702x; 1.7702x over previous
//
#include <hip/hip_runtime.h>
#include <math.h>

// DETR HungarianMatcher cost matrix on MI355X — round 15: inverted structure.
// 500 blocks x 1024 threads (16 waves), ROWS=32 rows/block. Thread <-> one
// target m = tid; row context from wave-uniform s_load (SALU, zero VALU);
// scalar NT dword stores (block writes full 4KB row per iteration).
// Registers ~25 -> lb(1024,2) spill-free; fetch 500x20KB ~= 10 MB.

#define NROWS 16000
#define NC 92
#define M_TGT 1024
#define TPB 1024
#define ROWS 32

__global__ __launch_bounds__(TPB, 2) void hungarian_cost_kernel(
    const float* __restrict__ logits,   // [NROWS, NC]
    const float* __restrict__ pboxes,   // [NROWS, 4] cxcywh
    const float* __restrict__ tboxes,   // [M_TGT, 4] cxcywh
    const int*   __restrict__ tlabels,  // [M_TGT]
    float* __restrict__ out)            // [NROWS, M_TGT]
{
    const int n0 = blockIdx.x * ROWS;
    const int t = threadIdx.x;          // 0..1023 == target index m
    const int lane = t & 63;
    const int wid  = t >> 6;            // 0..15

    __shared__ float negp[ROWS][NC];    // 2 - softmax prob

    // ---- softmax: wave `wid` handles rows 2*wid, 2*wid+1 (32 rows) ----
    #pragma unroll
    for (int j = 0; j < 2; ++j) {
        const int r = wid * 2 + j;
        const float* lg = logits + (size_t)(n0 + r) * NC;
        const float x0 = lg[lane];                 // lanes 0..63
        const bool  hi = (lane < NC - 64);         // lanes 0..27 cover 64..91
        const float x1 = hi ? lg[64 + lane] : -INFINITY;
        float mx = fmaxf(x0, x1);
        #pragma unroll
        for (int off = 32; off >= 1; off >>= 1)
            mx = fmaxf(mx, __shfl_xor(mx, off));
        const float e0 = __expf(x0 - mx);
        const float e1 = hi ? __expf(x1 - mx) : 0.0f;
        float s = e0 + e1;
        #pragma unroll
        for (int off = 32; off >= 1; off >>= 1)
            s += __shfl_xor(s, off);
        const float rs = __builtin_amdgcn_rcpf(s);
        negp[r][lane] = fmaf(-e0, rs, 2.0f);
        if (hi) negp[r][64 + lane] = fmaf(-e1, rs, 2.0f);
    }

    // ---- per-thread target context (one target) ----
    const float4 tb = reinterpret_cast<const float4*>(tboxes)[t];
    const float tcx = tb.x, tcy = tb.y, twd = tb.z, tht = tb.w;
    const float bx0 = fmaf(-0.5f, tb.z, tb.x), by0 = fmaf(-0.5f, tb.w, tb.y);
    const float bx1 = fmaf( 0.5f, tb.z, tb.x), by1 = fmaf( 0.5f, tb.w, tb.y);
    const float areab = tb.z * tb.w;
    int lbl = tlabels[t];
    lbl = (lbl < 0) ? 0 : (lbl > NC - 1 ? NC - 1 : lbl);
    __syncthreads();

    // ---- main loop: 32 rows, scalar NT store (full 4KB row per block) ----
    float cls = negp[0][lbl];
    float4 pb = reinterpret_cast<const float4*>(pboxes)[n0];   // uniform s_load

    #pragma unroll 4
    for (int r = 0; r < ROWS; ++r) {
        float clsN;
        float4 pbN;
        if (r + 1 < ROWS) {
            clsN = negp[r + 1][lbl];
            pbN = reinterpret_cast<const float4*>(pboxes)[n0 + r + 1];
        }

        // row context: all wave-uniform (SALU)
        const float ax0 = fmaf(-0.5f, pb.z, pb.x);
        const float ay0 = fmaf(-0.5f, pb.w, pb.y);
        const float ax1 = fmaf( 0.5f, pb.z, pb.x);
        const float ay1 = fmaf( 0.5f, pb.w, pb.y);
        const float area_a = pb.z * pb.w;

        const float cb = fabsf(pb.x - tcx) + fabsf(pb.y - tcy)
                       + fabsf(pb.z - twd) + fabsf(pb.w - tht);
        const float iwu = fminf(ax1, bx1) - fmaxf(ax0, bx0);
        const float ihu = fminf(ay1, by1) - fmaxf(ay0, by0);
        const float inter = fmaxf(iwu, 0.0f) * fmaxf(ihu, 0.0f);
        const float uni = area_a + areab - inter;
        const float ew = pb.z + twd - iwu;   // max(a1,b1)-min(a0,b0)
        const float eh = pb.w + tht - ihu;
        const float ae = ew * eh;
        const float h = fmaf(inter, __builtin_amdgcn_rcpf(uni),
                             uni * __builtin_amdgcn_rcpf(ae));
        const float cost = fmaf(5.0f, cb, cls) - 2.0f * h;

        __builtin_nontemporal_store(cost, out + ((size_t)(n0 + r) << 10) + t);

        cls = clsN;
        pb = pbN;
    }
}

extern "C" void kernel_launch(void* const* d_in, const int* in_sizes, int n_in,
                              void* d_out, int out_size, void* d_ws, size_t ws_size,
                              hipStream_t stream) {
    const float* logits  = (const float*)d_in[0];  // [16,1000,92]
    const float* pboxes  = (const float*)d_in[1];  // [16,1000,4]
    const float* tboxes  = (const float*)d_in[2];  // [1024,4]
    const int*   tlabels = (const int*)d_in[3];    // [1024]
    float* out = (float*)d_out;                    // [16,1000,1024]

    hungarian_cost_kernel<<<NROWS / ROWS, TPB, 0, stream>>>(
        logits, pboxes, tboxes, tlabels, out);
}